// Round 2
// baseline (161.203 us; speedup 1.0000x reference)
//
#include <hip/hip_runtime.h>
#include <hip/hip_bf16.h>

#define BSZ 8192
#define BTZ 8192
#define DD 64
#define NC 10
#define SHIFT2 20.0f   // log2-domain shift
#define LN2 0.69314718055994531f
#define LOG2E 1.44269504088896341f

typedef __attribute__((ext_vector_type(8))) short bf16x8;
typedef __attribute__((ext_vector_type(4))) float f32x4;

#if defined(__has_builtin)
#if __has_builtin(__builtin_amdgcn_exp2f)
#define EXP2(x) __builtin_amdgcn_exp2f(x)
#else
#define EXP2(x) exp2f(x)
#endif
#else
#define EXP2(x) exp2f(x)
#endif

__device__ __forceinline__ unsigned short f2bf_rne(float f) {
    unsigned int u = __float_as_uint(f);
    u += 0x7FFFu + ((u >> 16) & 1u);
    return (unsigned short)(u >> 16);
}

// Kernel A: f32 -> bf16 (RNE). src is pre-scaled by log2(e) so the GEMM
// directly produces M*log2e (exp2 domain). + src label histogram.
__global__ void kA(const float4* __restrict__ src4, const float4* __restrict__ tgt4,
                   const int* __restrict__ labels,
                   ushort4* __restrict__ srcb, ushort4* __restrict__ tgtb,
                   float* __restrict__ counts) {
    int tid = blockIdx.x * 256 + threadIdx.x;   // 131072 threads = 8192*64/4
    float4 s = src4[tid];
    ushort4 os;
    os.x = f2bf_rne(s.x * LOG2E); os.y = f2bf_rne(s.y * LOG2E);
    os.z = f2bf_rne(s.z * LOG2E); os.w = f2bf_rne(s.w * LOG2E);
    srcb[tid] = os;
    float4 t = tgt4[tid];
    ushort4 ot; ot.x = f2bf_rne(t.x); ot.y = f2bf_rne(t.y);
    ot.z = f2bf_rne(t.z); ot.w = f2bf_rne(t.w);
    tgtb[tid] = ot;
    if (tid < BSZ) atomicAdd(&counts[labels[tid]], 1.0f);
}

// Kernel B: per-tgt conf/cls -> colbias (log2 domain); confcount; class sums
// T (confident tgt rows) and SC (src rows by label).
__global__ void kB(const float* __restrict__ logits, const float* __restrict__ tgtf,
                   const float* __restrict__ srcf, const int* __restrict__ labels,
                   const float* __restrict__ counts,
                   float* __restrict__ colbias, float* __restrict__ confcount,
                   float* __restrict__ T, float* __restrict__ SC) {
    __shared__ int lcls[256];
    __shared__ float acc[4][NC * DD];
    __shared__ float hist[NC];
    int t = threadIdx.x;
    int i = blockIdx.x * 256 + t;

    float m1 = -3.0e38f, m2 = -3.0e38f; int cls = 0;
    #pragma unroll
    for (int c = 0; c < NC; ++c) {
        float v = logits[i * NC + c];
        if (v > m1) { m2 = m1; m1 = v; cls = c; }
        else if (v > m2) { m2 = v; }
    }
    bool conf = (m1 - m2) >= 0.1f;
    float cnt = counts[cls];
    colbias[i] = (conf && cnt > 0.0f) ? (log2f(cnt) - SHIFT2) : -1.0e30f;
    lcls[t] = conf ? cls : -1;
    if (t < NC) hist[t] = 0.0f;
    __syncthreads();
    if (conf) atomicAdd(&hist[cls], 1.0f);
    __syncthreads();
    if (t < NC) atomicAdd(&confcount[t], hist[t]);

    int rg = t >> 6, d = t & 63;
    #pragma unroll
    for (int c = 0; c < NC; ++c) acc[rg][c * DD + d] = 0.0f;
    __syncthreads();
    for (int r = 0; r < 64; ++r) {
        int c = lcls[rg * 64 + r];
        if (c >= 0) acc[rg][c * DD + d] += tgtf[(blockIdx.x * 256 + rg * 64 + r) * DD + d];
    }
    __syncthreads();
    for (int o = t; o < NC * DD; o += 256)
        atomicAdd(&T[o], acc[0][o] + acc[1][o] + acc[2][o] + acc[3][o]);
    __syncthreads();
    lcls[t] = labels[i];
    #pragma unroll
    for (int c = 0; c < NC; ++c) acc[rg][c * DD + d] = 0.0f;
    __syncthreads();
    for (int r = 0; r < 64; ++r) {
        int c = lcls[rg * 64 + r];
        acc[rg][c * DD + d] += srcf[(blockIdx.x * 256 + rg * 64 + r) * DD + d];
    }
    __syncthreads();
    for (int o = t; o < NC * DD; o += 256)
        atomicAdd(&SC[o], acc[0][o] + acc[1][o] + acc[2][o] + acc[3][o]);
}

// Kernel C: fused bf16 MFMA GEMM + exp2 row-sum.
// Grid: 2048 blocks = 128 rowgroups x 16 colchunks -> 8 blocks/CU.
// Block = 64 rows x 512 cols; the 4 waves split COLUMNS (128 each) so the
// per-row partials merge in LDS -> only 16 atomics/row across the grid.
// Column bias is folded into the MFMA accumulator init (C col = lane&15).
__global__ __launch_bounds__(256) void kC(const unsigned short* __restrict__ srcb,
                                          const unsigned short* __restrict__ tgtb,
                                          const float* __restrict__ colbias,
                                          float* __restrict__ S) {
    __shared__ float lds[4][64];
    int t = threadIdx.x;
    int w = t >> 6;
    int lane = t & 63;
    int l15 = lane & 15;
    int quad = lane >> 4;
    int colchunk = blockIdx.x & 15;
    int rowg = blockIdx.x >> 4;
    int row_base = rowg * 64;

    bf16x8 a[4][2];
    #pragma unroll
    for (int mb = 0; mb < 4; ++mb) {
        const bf16x8* p = (const bf16x8*)(srcb + (size_t)(row_base + mb * 16 + l15) * DD + quad * 8);
        a[mb][0] = p[0];   // k = quad*8 + j
        a[mb][1] = p[4];   // k = 32 + quad*8 + j
    }

    float rs[4][4];
    #pragma unroll
    for (int mb = 0; mb < 4; ++mb)
        #pragma unroll
        for (int r = 0; r < 4; ++r) rs[mb][r] = 0.0f;

    int col0 = colchunk * 512 + w * 128;
    #pragma unroll 2
    for (int ct = 0; ct < 8; ++ct) {
        int cb = col0 + ct * 16;
        const bf16x8* q = (const bf16x8*)(tgtb + (size_t)(cb + l15) * DD + quad * 8);
        bf16x8 b0 = q[0];
        bf16x8 b1 = q[4];
        float cb2 = colbias[cb + l15];
        #pragma unroll
        for (int mb = 0; mb < 4; ++mb) {
            f32x4 acc = {cb2, cb2, cb2, cb2};
            acc = __builtin_amdgcn_mfma_f32_16x16x32_bf16(a[mb][0], b0, acc, 0, 0, 0);
            acc = __builtin_amdgcn_mfma_f32_16x16x32_bf16(a[mb][1], b1, acc, 0, 0, 0);
            #pragma unroll
            for (int r = 0; r < 4; ++r)
                rs[mb][r] += EXP2(acc[r]);
        }
    }

    // intra-wave: reduce over the 16 column-lanes; then cross-wave via LDS
    #pragma unroll
    for (int mb = 0; mb < 4; ++mb) {
        #pragma unroll
        for (int r = 0; r < 4; ++r) {
            float v = rs[mb][r];
            v += __shfl_xor(v, 1);
            v += __shfl_xor(v, 2);
            v += __shfl_xor(v, 4);
            v += __shfl_xor(v, 8);
            if (l15 == 0) lds[w][mb * 16 + quad * 4 + r] = v;
        }
    }
    __syncthreads();
    if (t < 64)
        atomicAdd(&S[row_base + t], lds[0][t] + lds[1][t] + lds[2][t] + lds[3][t]);
}

// Kernel D: single-block finale. L[j] = (log2(S[j]) + SHIFT2) * ln2.
__global__ void kD(const float* __restrict__ S, const int* __restrict__ labels,
                   const float* __restrict__ counts, const float* __restrict__ confcount,
                   const float* __restrict__ T, const float* __restrict__ SC,
                   float* __restrict__ out) {
    int t = threadIdx.x;
    float termL = 0.0f, term1 = 0.0f, P = 0.0f;
    for (int j = t; j < BSZ; j += 256) {
        float L = (log2f(S[j]) + SHIFT2) * LN2;
        termL += confcount[labels[j]] * L;
    }
    for (int o = t; o < NC * DD; o += 256) term1 += SC[o] * T[o];
    for (int o = t; o < NC; o += 256) P += counts[o] * confcount[o];

    __shared__ float redL[4], red1[4], redP[4];
    int w = t >> 6, lane = t & 63;
    float v1 = termL, v2 = term1, v3 = P;
    #pragma unroll
    for (int m = 1; m < 64; m <<= 1) {
        v1 += __shfl_xor(v1, m);
        v2 += __shfl_xor(v2, m);
        v3 += __shfl_xor(v3, m);
    }
    if (lane == 0) { redL[w] = v1; red1[w] = v2; redP[w] = v3; }
    __syncthreads();
    if (t == 0) {
        float tl = redL[0] + redL[1] + redL[2] + redL[3];
        float t1 = red1[0] + red1[1] + red1[2] + red1[3];
        float p  = redP[0] + redP[1] + redP[2] + redP[3];
        out[0] = (t1 - tl) / (-(float)BSZ * p);
    }
}

extern "C" void kernel_launch(void* const* d_in, const int* in_sizes, int n_in,
                              void* d_out, int out_size, void* d_ws, size_t ws_size,
                              hipStream_t stream) {
    const float* src    = (const float*)d_in[0];
    const int*   labels = (const int*)d_in[1];
    const float* tgt    = (const float*)d_in[2];
    const float* logits = (const float*)d_in[3];

    char* ws = (char*)d_ws;
    float* S         = (float*)(ws + 0);           // 32768 B
    float* counts    = (float*)(ws + 32768);       // 64 B
    float* confcount = (float*)(ws + 32832);       // 64 B
    float* T         = (float*)(ws + 32896);       // 2560 B
    float* SC        = (float*)(ws + 35456);       // 2560 B
    float* colbias   = (float*)(ws + 40960);       // 32768 B (fully written by kB)
    unsigned short* srcb = (unsigned short*)(ws + 73728);            // 1 MiB
    unsigned short* tgtb = (unsigned short*)(ws + 73728 + 1048576);  // 1 MiB

    hipMemsetAsync(ws, 0, 40960, stream);  // zero S/counts/confcount/T/SC
    kA<<<512, 256, 0, stream>>>((const float4*)src, (const float4*)tgt, labels,
                                (ushort4*)srcb, (ushort4*)tgtb, counts);
    kB<<<32, 256, 0, stream>>>(logits, tgt, src, labels, counts,
                               colbias, confcount, T, SC);
    kC<<<2048, 256, 0, stream>>>(srcb, tgtb, colbias, S);
    kD<<<1, 256, 0, stream>>>(S, labels, counts, confcount, T, SC, (float*)d_out);
}

// Round 3
// 109.919 us; speedup vs baseline: 1.4666x; 1.4666x over previous
//
#include <hip/hip_runtime.h>
#include <hip/hip_bf16.h>

#define BSZ 8192
#define BTZ 8192
#define DD 64
#define NC 10
#define SHIFT2 20.0f   // log2-domain shift
#define LN2 0.69314718055994531f
#define LOG2E 1.44269504088896341f

typedef __attribute__((ext_vector_type(8))) short bf16x8;
typedef __attribute__((ext_vector_type(4))) float f32x4;

#if defined(__has_builtin)
#if __has_builtin(__builtin_amdgcn_exp2f)
#define EXP2(x) __builtin_amdgcn_exp2f(x)
#else
#define EXP2(x) exp2f(x)
#endif
#else
#define EXP2(x) exp2f(x)
#endif

__device__ __forceinline__ unsigned short f2bf_rne(float f) {
    unsigned int u = __float_as_uint(f);
    u += 0x7FFFu + ((u >> 16) & 1u);
    return (unsigned short)(u >> 16);
}

// Kernel A: f32 -> bf16 (RNE); src pre-scaled by log2(e). Blocks 0..31 also
// build per-block label-histogram partials (LDS only -> slot; NO global atomics).
__global__ void kA(const float4* __restrict__ src4, const float4* __restrict__ tgt4,
                   const int* __restrict__ labels,
                   ushort4* __restrict__ srcb, ushort4* __restrict__ tgtb,
                   float* __restrict__ cnt_part) {
    __shared__ float hist[NC];
    int t = threadIdx.x;
    int tid = blockIdx.x * 256 + t;   // 131072 threads = 8192*64/4
    float4 s = src4[tid];
    ushort4 os;
    os.x = f2bf_rne(s.x * LOG2E); os.y = f2bf_rne(s.y * LOG2E);
    os.z = f2bf_rne(s.z * LOG2E); os.w = f2bf_rne(s.w * LOG2E);
    srcb[tid] = os;
    float4 v = tgt4[tid];
    ushort4 ot; ot.x = f2bf_rne(v.x); ot.y = f2bf_rne(v.y);
    ot.z = f2bf_rne(v.z); ot.w = f2bf_rne(v.w);
    tgtb[tid] = ot;

    if (blockIdx.x < 32) {
        if (t < NC) hist[t] = 0.0f;
        __syncthreads();
        atomicAdd(&hist[labels[tid]], 1.0f);
        __syncthreads();
        if (t < NC) cnt_part[blockIdx.x * NC + t] = hist[t];
    }
}

// Kernel B: per-tgt top2/cls/conf -> colbias (log2 domain) + cls byte;
// per-block confcount partials; zeroes S. counts reduced from partials in LDS.
__global__ void kB(const float* __restrict__ logits,
                   const float* __restrict__ cnt_part,
                   float* __restrict__ colbias, unsigned char* __restrict__ cls8,
                   float* __restrict__ cc_part, float* __restrict__ S) {
    __shared__ float lcnt[NC];
    __shared__ float hist[NC];
    int t = threadIdx.x;
    int i = blockIdx.x * 256 + t;

    if (t < NC) {
        float c = 0.0f;
        #pragma unroll
        for (int b = 0; b < 32; ++b) c += cnt_part[b * NC + t];
        lcnt[t] = c;
        hist[t] = 0.0f;
    }

    float m1 = -3.0e38f, m2 = -3.0e38f; int cls = 0;
    #pragma unroll
    for (int c = 0; c < NC; ++c) {
        float v = logits[i * NC + c];
        if (v > m1) { m2 = m1; m1 = v; cls = c; }
        else if (v > m2) { m2 = v; }
    }
    bool conf = (m1 - m2) >= 0.1f;
    __syncthreads();
    float cnt = lcnt[cls];
    bool live = conf && (cnt > 0.0f);
    colbias[i] = live ? (log2f(cnt) - SHIFT2) : -1.0e30f;
    cls8[i] = live ? (unsigned char)cls : (unsigned char)255;
    S[i] = 0.0f;
    if (conf) atomicAdd(&hist[cls], 1.0f);
    __syncthreads();
    if (t < NC) cc_part[blockIdx.x * NC + t] = hist[t];
}

// Kernel C: fused bf16 MFMA GEMM + exp2 row-sum + inline term1 (pair-sum of M).
// Grid: 2048 blocks = 128 rowgroups x 16 colchunks. Block = 64 rows x 512 cols;
// 4 waves split columns. Column bias folded into MFMA accumulator init.
__global__ __launch_bounds__(256) void kC(const unsigned short* __restrict__ srcb,
                                          const unsigned short* __restrict__ tgtb,
                                          const float* __restrict__ colbias,
                                          const unsigned char* __restrict__ cls8,
                                          const int* __restrict__ labels,
                                          float* __restrict__ S,
                                          float* __restrict__ term1_part) {
    __shared__ float lds[4][64];
    __shared__ float t1red[4];
    int t = threadIdx.x;
    int w = t >> 6;
    int lane = t & 63;
    int l15 = lane & 15;
    int quad = lane >> 4;
    int colchunk = blockIdx.x & 15;
    int rowg = blockIdx.x >> 4;
    int row_base = rowg * 64;

    bf16x8 a[4][2];
    int rl[4][4];
    #pragma unroll
    for (int mb = 0; mb < 4; ++mb) {
        const bf16x8* p = (const bf16x8*)(srcb + (size_t)(row_base + mb * 16 + l15) * DD + quad * 8);
        a[mb][0] = p[0];   // k = quad*8 + j
        a[mb][1] = p[4];   // k = 32 + quad*8 + j
        #pragma unroll
        for (int r = 0; r < 4; ++r)
            rl[mb][r] = labels[row_base + mb * 16 + quad * 4 + r];
    }

    float rs[4][4];
    #pragma unroll
    for (int mb = 0; mb < 4; ++mb)
        #pragma unroll
        for (int r = 0; r < 4; ++r) rs[mb][r] = 0.0f;
    float t1p = 0.0f;

    int col0 = colchunk * 512 + w * 128;
    #pragma unroll 2
    for (int ct = 0; ct < 8; ++ct) {
        int cb = col0 + ct * 16;
        const bf16x8* q = (const bf16x8*)(tgtb + (size_t)(cb + l15) * DD + quad * 8);
        bf16x8 b0 = q[0];
        bf16x8 b1 = q[4];
        float cb2 = colbias[cb + l15];
        int ccls = (int)cls8[cb + l15];
        #pragma unroll
        for (int mb = 0; mb < 4; ++mb) {
            f32x4 acc = {cb2, cb2, cb2, cb2};
            acc = __builtin_amdgcn_mfma_f32_16x16x32_bf16(a[mb][0], b0, acc, 0, 0, 0);
            acc = __builtin_amdgcn_mfma_f32_16x16x32_bf16(a[mb][1], b1, acc, 0, 0, 0);
            #pragma unroll
            for (int r = 0; r < 4; ++r) {
                float e = acc[r];
                rs[mb][r] += EXP2(e);
                t1p += (ccls == rl[mb][r]) ? (e - cb2) : 0.0f;
            }
        }
    }

    // row sums: reduce over 16 column-lanes per quad, cross-wave via LDS
    #pragma unroll
    for (int mb = 0; mb < 4; ++mb) {
        #pragma unroll
        for (int r = 0; r < 4; ++r) {
            float v = rs[mb][r];
            v += __shfl_xor(v, 1);
            v += __shfl_xor(v, 2);
            v += __shfl_xor(v, 4);
            v += __shfl_xor(v, 8);
            if (l15 == 0) lds[w][mb * 16 + quad * 4 + r] = v;
        }
    }
    // term1: full-wave reduce then LDS
    float tv = t1p;
    #pragma unroll
    for (int m = 1; m < 64; m <<= 1) tv += __shfl_xor(tv, m);
    if (lane == 0) t1red[w] = tv;
    __syncthreads();
    if (t < 64)
        atomicAdd(&S[row_base + t], lds[0][t] + lds[1][t] + lds[2][t] + lds[3][t]);
    if (t == 128)
        term1_part[blockIdx.x] = t1red[0] + t1red[1] + t1red[2] + t1red[3];
}

// Kernel D: single-block finale.
__global__ void kD(const float* __restrict__ S, const int* __restrict__ labels,
                   const float* __restrict__ cnt_part, const float* __restrict__ cc_part,
                   const float* __restrict__ term1_part,
                   float* __restrict__ out) {
    __shared__ float counts[NC], cc[NC];
    int t = threadIdx.x;
    if (t < NC) {
        float c0 = 0.0f, c1 = 0.0f;
        #pragma unroll
        for (int b = 0; b < 32; ++b) { c0 += cnt_part[b * NC + t]; c1 += cc_part[b * NC + t]; }
        counts[t] = c0; cc[t] = c1;
    }
    __syncthreads();

    float termL = 0.0f, term1 = 0.0f, P = 0.0f;
    for (int j = t; j < BSZ; j += 256) {
        float L = (log2f(S[j]) + SHIFT2) * LN2;
        termL += cc[labels[j]] * L;
    }
    for (int o = t; o < 2048; o += 256) term1 += term1_part[o];
    if (t < NC) P = counts[t] * cc[t];

    __shared__ float redL[4], red1[4], redP[4];
    int w = t >> 6, lane = t & 63;
    float v1 = termL, v2 = term1, v3 = P;
    #pragma unroll
    for (int m = 1; m < 64; m <<= 1) {
        v1 += __shfl_xor(v1, m);
        v2 += __shfl_xor(v2, m);
        v3 += __shfl_xor(v3, m);
    }
    if (lane == 0) { redL[w] = v1; red1[w] = v2; redP[w] = v3; }
    __syncthreads();
    if (t == 0) {
        float tl = redL[0] + redL[1] + redL[2] + redL[3];
        float t1 = (red1[0] + red1[1] + red1[2] + red1[3]) * LN2;
        float p  = redP[0] + redP[1] + redP[2] + redP[3];
        out[0] = (t1 - tl) / (-(float)BSZ * p);
    }
}

extern "C" void kernel_launch(void* const* d_in, const int* in_sizes, int n_in,
                              void* d_out, int out_size, void* d_ws, size_t ws_size,
                              hipStream_t stream) {
    const float* src    = (const float*)d_in[0];
    const int*   labels = (const int*)d_in[1];
    const float* tgt    = (const float*)d_in[2];
    const float* logits = (const float*)d_in[3];

    char* ws = (char*)d_ws;
    float* S          = (float*)(ws + 0);        // 32768 B, zeroed by kB
    float* cnt_part   = (float*)(ws + 32768);    // 1280 B, written by kA
    float* cc_part    = (float*)(ws + 34048);    // 1280 B, written by kB
    float* term1_part = (float*)(ws + 35328);    // 8192 B, written by kC
    float* colbias    = (float*)(ws + 65536);    // 32768 B, written by kB
    unsigned char* cls8 = (unsigned char*)(ws + 98304);   // 8192 B, written by kB
    unsigned short* srcb = (unsigned short*)(ws + 131072);            // 1 MiB
    unsigned short* tgtb = (unsigned short*)(ws + 131072 + 1048576);  // 1 MiB

    kA<<<512, 256, 0, stream>>>((const float4*)src, (const float4*)tgt, labels,
                                (ushort4*)srcb, (ushort4*)tgtb, cnt_part);
    kB<<<32, 256, 0, stream>>>(logits, cnt_part, colbias, cls8, cc_part, S);
    kC<<<2048, 256, 0, stream>>>(srcb, tgtb, colbias, cls8, labels, S, term1_part);
    kD<<<1, 256, 0, stream>>>(S, labels, cnt_part, cc_part, term1_part, (float*)d_out);
}